// Round 5
// baseline (341.572 us; speedup 1.0000x reference)
//
#include <hip/hip_runtime.h>
#include <hip/hip_bf16.h>
#include <cstdint>

#define BN_SCALEF 0.99999500003749975f  // 1/sqrt(1+1e-5)
#define EXP_SHIFT 4.0f

// Problem constants: B=128, N=200, F=768, H=8, Fo=32, Fh=256

typedef _Float16 half8 __attribute__((ext_vector_type(8)));
typedef _Float16 half4 __attribute__((ext_vector_type(4)));
typedef float floatx4 __attribute__((ext_vector_type(4)));

// ---------------------------------------------------------------- prep: pack_mask + Wcat^T + W2t  (one launch)

__global__ __launch_bounds__(256) void prep(const int* __restrict__ adj,
                                            const float* __restrict__ W_heads,
                                            const float* __restrict__ Ws_in,
                                            const float* __restrict__ Wp_in,
                                            const float* __restrict__ Wq_in,
                                            unsigned int* __restrict__ maskw,
                                            _Float16* __restrict__ Bt,
                                            float* __restrict__ W2t) {
    int blk = blockIdx.x;
    int t = threadIdx.x;
    if (blk < 1600) {
        int w = t >> 6, lane = t & 63;
        for (int task = w; task < 64; task += 4) {
            int r = blk * 16 + (task >> 2);
            int c0 = (task & 3) * 64;
            int j = c0 + lane;
            bool v = (j < 200) && (adj[(size_t)r * 200 + j] > 0);
            unsigned long long m = __ballot(v ? 1 : 0);
            if (lane == 0) {
                maskw[r * 8 + (c0 >> 5)]     = (unsigned int)(m & 0xffffffffULL);
                maskw[r * 8 + (c0 >> 5) + 1] = (unsigned int)(m >> 32);
            }
        }
    } else if (blk < 1792) {
        __shared__ float ld[32][36];
        int blk2 = blk - 1600;          // h = blk2/24, f-tile = blk2%24
        int h = blk2 / 24, f0 = (blk2 % 24) * 32;
        int idx = t * 4;
        int fr = idx >> 5, o0 = idx & 31;
        float4 v = *(const float4*)&W_heads[(size_t)h * 24576 + (size_t)(f0 + fr) * 32 + o0];
        ld[fr][o0] = v.x; ld[fr][o0 + 1] = v.y; ld[fr][o0 + 2] = v.z; ld[fr][o0 + 3] = v.w;
        __syncthreads();
        int o = idx >> 5, fr0 = idx & 31;
        half4 hv;
#pragma unroll
        for (int u = 0; u < 4; ++u) hv[u] = (_Float16)ld[fr0 + u][o];
        *(half4*)&Bt[(size_t)(h * 32 + o) * 768 + f0 + fr0] = hv;
    } else {
        for (int c = 0; c < 36; ++c) {
            float v;
            if (c < 2)      v = Ws_in[t * 2 + c];
            else if (c < 4) v = Wp_in[t * 2 + (c - 2)];
            else            v = Wq_in[t * 32 + (c - 4)];
            W2t[c * 256 + t] = v;
        }
    }
}

// ---------------------------------------------------------------- GEMM1: LDS-free streaming MFMA
// h16[25600,256] = A[25600,768] fp32 @ Bt^T (f16 [256][768])
// block = 32 rows x 256 cols; 4 waves, wave w = cols w*64..+64 (2x4 16x16 tiles)
// A-frags + B-frags loaded straight from global in MFMA layout; no LDS, no barriers.

__global__ __launch_bounds__(256) void gemm1_stream(const float* __restrict__ A,
                                                    const _Float16* __restrict__ Bt,
                                                    _Float16* __restrict__ h16) {
    int t = threadIdx.x;
    int w = t >> 6, lane = t & 63;
    int l16 = lane & 15, quad = lane >> 4;
    int m0 = blockIdx.x * 32;       // 800 blocks
    int c0 = w * 64;

    const float* Ap0 = &A[(size_t)(m0 + l16) * 768 + quad * 8];
    const float* Ap1 = Ap0 + 16 * 768;
    const _Float16* Bp0 = &Bt[(size_t)(c0 + l16) * 768 + quad * 8];
    const _Float16* Bp1 = Bp0 + 16 * 768;
    const _Float16* Bp2 = Bp0 + 32 * 768;
    const _Float16* Bp3 = Bp0 + 48 * 768;

    floatx4 acc[2][4];
#pragma unroll
    for (int i = 0; i < 2; ++i)
#pragma unroll
        for (int j = 0; j < 4; ++j) acc[i][j] = (floatx4){0.f, 0.f, 0.f, 0.f};

    float4 a0a = *(const float4*)(Ap0), a0b = *(const float4*)(Ap0 + 4);
    float4 a1a = *(const float4*)(Ap1), a1b = *(const float4*)(Ap1 + 4);
    uint4 bq0 = *(const uint4*)(Bp0);
    uint4 bq1 = *(const uint4*)(Bp1);
    uint4 bq2 = *(const uint4*)(Bp2);
    uint4 bq3 = *(const uint4*)(Bp3);

    for (int kt = 0; kt < 24; ++kt) {
        // capture current fragments
        half8 af0, af1;
        af0[0] = (_Float16)a0a.x; af0[1] = (_Float16)a0a.y; af0[2] = (_Float16)a0a.z; af0[3] = (_Float16)a0a.w;
        af0[4] = (_Float16)a0b.x; af0[5] = (_Float16)a0b.y; af0[6] = (_Float16)a0b.z; af0[7] = (_Float16)a0b.w;
        af1[0] = (_Float16)a1a.x; af1[1] = (_Float16)a1a.y; af1[2] = (_Float16)a1a.z; af1[3] = (_Float16)a1a.w;
        af1[4] = (_Float16)a1b.x; af1[5] = (_Float16)a1b.y; af1[6] = (_Float16)a1b.z; af1[7] = (_Float16)a1b.w;
        half8 bf0 = *(half8*)&bq0, bf1 = *(half8*)&bq1, bf2 = *(half8*)&bq2, bf3 = *(half8*)&bq3;
        // prefetch next k-step
        if (kt < 23) {
            int ko = (kt + 1) * 32;
            a0a = *(const float4*)(Ap0 + ko); a0b = *(const float4*)(Ap0 + ko + 4);
            a1a = *(const float4*)(Ap1 + ko); a1b = *(const float4*)(Ap1 + ko + 4);
            bq0 = *(const uint4*)(Bp0 + ko);
            bq1 = *(const uint4*)(Bp1 + ko);
            bq2 = *(const uint4*)(Bp2 + ko);
            bq3 = *(const uint4*)(Bp3 + ko);
        }
        acc[0][0] = __builtin_amdgcn_mfma_f32_16x16x32_f16(af0, bf0, acc[0][0], 0, 0, 0);
        acc[0][1] = __builtin_amdgcn_mfma_f32_16x16x32_f16(af0, bf1, acc[0][1], 0, 0, 0);
        acc[0][2] = __builtin_amdgcn_mfma_f32_16x16x32_f16(af0, bf2, acc[0][2], 0, 0, 0);
        acc[0][3] = __builtin_amdgcn_mfma_f32_16x16x32_f16(af0, bf3, acc[0][3], 0, 0, 0);
        acc[1][0] = __builtin_amdgcn_mfma_f32_16x16x32_f16(af1, bf0, acc[1][0], 0, 0, 0);
        acc[1][1] = __builtin_amdgcn_mfma_f32_16x16x32_f16(af1, bf1, acc[1][1], 0, 0, 0);
        acc[1][2] = __builtin_amdgcn_mfma_f32_16x16x32_f16(af1, bf2, acc[1][2], 0, 0, 0);
        acc[1][3] = __builtin_amdgcn_mfma_f32_16x16x32_f16(af1, bf3, acc[1][3], 0, 0, 0);
    }

#pragma unroll
    for (int mt = 0; mt < 2; ++mt)
#pragma unroll
        for (int nt = 0; nt < 4; ++nt) {
            int gc = c0 + nt * 16 + l16;
#pragma unroll
            for (int r = 0; r < 4; ++r) {
                int gr = m0 + mt * 16 + quad * 4 + r;
                h16[(size_t)gr * 256 + gc] = (_Float16)acc[mt][nt][r];
            }
        }
}

// ---------------------------------------------------------------- head attention via MFMA (h16 in, x16 out)
// s1/s2 computed in-block from the LDS h-tile.

__global__ __launch_bounds__(256) void attn_heads_mfma(
    const _Float16* __restrict__ h16,
    const float* __restrict__ a_h,
    const unsigned int* __restrict__ maskw,
    const float* __restrict__ bnh_g, const float* __restrict__ bnh_b,
    const float* __restrict__ bnt_g, const float* __restrict__ bnt_b,
    _Float16* __restrict__ x16) {
    __shared__ __align__(16) _Float16 Bs[48 * 228];   // [n][k]: n<32 h^T, n=32 ones, rest 0
    __shared__ __align__(16) _Float16 Ps[64 * 228];   // 4 waves x 16-row slabs
    __shared__ float s1s[256], s2s[256];
    int hb = blockIdx.x;
    int h = hb >> 7, b = hb & 127;
    int t = threadIdx.x;

    unsigned long long* bz = (unsigned long long*)Bs;
    for (int idx = t; idx < (48 * 228) / 4; idx += 256) bz[idx] = 0ULL;
    __syncthreads();
    for (int idx = t; idx < 800; idx += 256) {
        int j = idx >> 2, w8 = (idx & 3) * 8;
        half8 v = *(const half8*)&h16[(size_t)(b * 200 + j) * 256 + h * 32 + w8];
#pragma unroll
        for (int u = 0; u < 8; ++u) Bs[(w8 + u) * 228 + j] = v[u];
    }
    if (t < 200) Bs[32 * 228 + t] = (_Float16)1.0f;
    __syncthreads();

    // s1/s2 from the LDS h-tile (f16 h, fp32 accumulate)
    if (t < 200) {
        float acc1 = 0.f, acc2 = 0.f;
        const float* ab = &a_h[h * 64];
#pragma unroll
        for (int o = 0; o < 32; ++o) {
            float hv = (float)Bs[o * 228 + t];
            acc1 += hv * ab[o];
            acc2 += hv * ab[32 + o];
        }
        s1s[t] = acc1; s2s[t] = acc2;
    } else {
        s1s[t] = 0.f; s2s[t] = 0.f;
    }
    __syncthreads();

    int w = t >> 6, lane = t & 63;
    int l16 = lane & 15, quad = lane >> 4;
    _Float16* Pw = &Ps[w * 16 * 228];

    int j0 = lane * 4;
    float4 s2r = *(const float4*)&s2s[j0];

    for (int tile = w; tile < 13; tile += 4) {
        int i_base = tile * 16;
        int nrows = (i_base + 16 <= 200) ? 16 : (200 - i_base);
        for (int r16 = 0; r16 < nrows; ++r16) {
            int i = i_base + r16;
            float s1v = s1s[i];
            unsigned int mw = maskw[(size_t)(b * 200 + i) * 8 + (lane >> 3)];
            half4 pv;
#pragma unroll
            for (int q = 0; q < 4; ++q) {
                float e = s1v + ((const float*)&s2r)[q];
                e = fmaxf(e, 0.3f * e);
                float p = ((mw >> ((j0 + q) & 31)) & 1u) ? __expf(e - EXP_SHIFT) : 0.f;
                pv[q] = (_Float16)p;
            }
            if (j0 < 228) *(half4*)&Pw[r16 * 228 + j0] = pv;
        }
        floatx4 acc0 = {0.f, 0.f, 0.f, 0.f};
        floatx4 acc1 = {0.f, 0.f, 0.f, 0.f};
        floatx4 acc2 = {0.f, 0.f, 0.f, 0.f};
#pragma unroll
        for (int kt = 0; kt < 7; ++kt) {
            half8 af = *(half8*)&Pw[l16 * 228 + kt * 32 + quad * 8];
            half8 b0 = *(half8*)&Bs[(l16) * 228 + kt * 32 + quad * 8];
            half8 b1 = *(half8*)&Bs[(16 + l16) * 228 + kt * 32 + quad * 8];
            half8 b2 = *(half8*)&Bs[(32 + l16) * 228 + kt * 32 + quad * 8];
            acc0 = __builtin_amdgcn_mfma_f32_16x16x32_f16(af, b0, acc0, 0, 0, 0);
            acc1 = __builtin_amdgcn_mfma_f32_16x16x32_f16(af, b1, acc1, 0, 0, 0);
            acc2 = __builtin_amdgcn_mfma_f32_16x16x32_f16(af, b2, acc2, 0, 0, 0);
        }
#pragma unroll
        for (int r = 0; r < 4; ++r) {
            int i = i_base + quad * 4 + r;
            float rsum = __shfl(acc2[r], (lane & 48), 64);
            if (i < 200) {
                float inv = 1.f / rsum;
                float g1 = BN_SCALEF * bnh_g[h * 200 + i], c1 = bnh_b[h * 200 + i];
                float g2 = BN_SCALEF * bnt_g[i], c2 = bnt_b[i];
                float v0 = acc0[r] * inv * g1 + c1;
                v0 = v0 > 0.f ? v0 : __expf(v0) - 1.f;
                v0 = v0 * g2 + c2;
                float v1 = acc1[r] * inv * g1 + c1;
                v1 = v1 > 0.f ? v1 : __expf(v1) - 1.f;
                v1 = v1 * g2 + c2;
                size_t base = (size_t)(b * 200 + i) * 256 + h * 32;
                x16[base + l16]      = (_Float16)v0;
                x16[base + 16 + l16] = (_Float16)v1;
            }
        }
    }
}

// ---------------------------------------------------------------- GEMM2 (x16 f16 in) + fused s12_second

__global__ __launch_bounds__(256) void gemm2s(const _Float16* __restrict__ X,
                                              const float* __restrict__ W2t,
                                              const float* __restrict__ a_sent,
                                              const float* __restrict__ a_para,
                                              const float* __restrict__ a_q,
                                              float* __restrict__ H2,
                                              float* __restrict__ sv) {
    __shared__ __align__(16) float Ws[36 * 260];
    __shared__ float Hs[128][37];
    int t = threadIdx.x;
#pragma unroll
    for (int rep = 0; rep < 9; ++rep) {
        int fidx = rep * 1024 + t * 4;
        int c = fidx >> 8, k = fidx & 255;
        *(float4*)&Ws[c * 260 + k] = *(const float4*)&W2t[fidx];
    }
    __syncthreads();
    int cg = t & 3, rt = t >> 2;
    int row0 = blockIdx.x * 128 + rt * 2;
    float acc[2][9] = {};
    for (int k = 0; k < 256; k += 8) {
        half8 x0 = *(const half8*)&X[(size_t)row0 * 256 + k];
        half8 x1 = *(const half8*)&X[(size_t)(row0 + 1) * 256 + k];
        float xf0[8], xf1[8];
#pragma unroll
        for (int u = 0; u < 8; ++u) { xf0[u] = (float)x0[u]; xf1[u] = (float)x1[u]; }
#pragma unroll
        for (int c = 0; c < 9; ++c) {
            const float* wr = &Ws[(cg * 9 + c) * 260 + k];
            float4 wa = *(float4*)wr;
            float4 wb = *(float4*)(wr + 4);
            acc[0][c] += xf0[0] * wa.x + xf0[1] * wa.y + xf0[2] * wa.z + xf0[3] * wa.w
                       + xf0[4] * wb.x + xf0[5] * wb.y + xf0[6] * wb.z + xf0[7] * wb.w;
            acc[1][c] += xf1[0] * wa.x + xf1[1] * wa.y + xf1[2] * wa.z + xf1[3] * wa.w
                       + xf1[4] * wb.x + xf1[5] * wb.y + xf1[6] * wb.z + xf1[7] * wb.w;
        }
    }
#pragma unroll
    for (int rr = 0; rr < 2; ++rr)
#pragma unroll
        for (int c = 0; c < 9; ++c) {
            H2[(size_t)(row0 + rr) * 36 + cg * 9 + c] = acc[rr][c];
            Hs[rt * 2 + rr][cg * 9 + c] = acc[rr][c];
        }
    __syncthreads();
    if (t < 128) {
        int row = blockIdx.x * 128 + t;
        float h0 = Hs[t][0], h1 = Hs[t][1], h2v = Hs[t][2], h3 = Hs[t][3];
        sv[row]          = h0 * a_sent[0] + h1 * a_sent[1];
        sv[25600 + row]  = h0 * a_sent[2] + h1 * a_sent[3];
        sv[51200 + row]  = h2v * a_para[0] + h3 * a_para[1];
        sv[76800 + row]  = h2v * a_para[2] + h3 * a_para[3];
        float aq1 = 0.f, aq2 = 0.f;
#pragma unroll
        for (int o = 0; o < 32; ++o) {
            float hv = Hs[t][4 + o];
            aq1 += hv * a_q[o];
            aq2 += hv * a_q[32 + o];
        }
        sv[102400 + row] = aq1;
        sv[128000 + row] = aq2;
    }
}

// ---------------------------------------------------------------- sent+para attention + q attention (grid y: 0,1=sp chunks, 2=q)

__global__ __launch_bounds__(256) void attn_spq(const float* __restrict__ H2,
                                                const float* __restrict__ sv,
                                                const unsigned int* __restrict__ maskw,
                                                const float* __restrict__ bns_g, const float* __restrict__ bns_b,
                                                const float* __restrict__ bnp_g, const float* __restrict__ bnp_b,
                                                const float* __restrict__ bnq_g, const float* __restrict__ bnq_b,
                                                const float* __restrict__ W2, float* __restrict__ out) {
    int b = blockIdx.x;
    int t = threadIdx.x;
    if (blockIdx.y == 2) {
        __shared__ float p_lds[200];
        __shared__ float redd[4];
        __shared__ float red2[256];
        float s1v = sv[102400 + b * 200];
        float p = 0.f;
        if (t < 200) {
            unsigned int mw = maskw[(size_t)(b * 200) * 8 + (t >> 5)];
            if ((mw >> (t & 31)) & 1u) {
                float x = s1v + sv[128000 + b * 200 + t];
                x = fmaxf(x, 0.3f * x);
                p = __expf(x - EXP_SHIFT);
            }
            p_lds[t] = p;
        }
        float ds = p;
        for (int off = 32; off; off >>= 1) ds += __shfl_xor(ds, off, 64);
        if ((t & 63) == 0) redd[t >> 6] = ds;
        __syncthreads();
        ds = redd[0] + redd[1] + redd[2] + redd[3];
        int o = t & 31, g = t >> 5;
        float acc = 0.f;
        for (int j = g; j < 200; j += 8)
            acc += p_lds[j] * H2[(size_t)(b * 200 + j) * 36 + 4 + o];
        red2[t] = acc;
        __syncthreads();
        if (t < 32) {
            float s = 0.f;
#pragma unroll
            for (int gg = 0; gg < 8; ++gg) s += red2[gg * 32 + t];
            float qv = (s / ds) * (BN_SCALEF * bnq_g[0]) + bnq_b[0];
            float c0 = qv * W2[t * 2], c1 = qv * W2[t * 2 + 1];
#pragma unroll
            for (int off = 16; off; off >>= 1) {
                c0 += __shfl_xor(c0, off, 64);
                c1 += __shfl_xor(c1, off, 64);
            }
            if (t == 0) {
                out[102400 + b * 2 + 0] = c0 > 0.f ? c0 : __expf(c0) - 1.f;
                out[102400 + b * 2 + 1] = c1 > 0.f ? c1 : __expf(c1) - 1.f;
            }
        }
        return;
    }
    __shared__ float s2s[200], s2p[200];
    __shared__ __align__(16) float hsp[200 * 4];
    int chunk = blockIdx.y;
    if (t < 200) {
        s2s[t] = sv[25600 + b * 200 + t];
        s2p[t] = sv[76800 + b * 200 + t];
    }
    for (int idx = t; idx < 800; idx += 256) {
        int j = idx >> 2, c = idx & 3;
        hsp[idx] = H2[(size_t)(b * 200 + j) * 36 + c];
    }
    __syncthreads();
    int w = t >> 6, lane = t & 63;
    for (int it = 0; it < 25; ++it) {
        int i = chunk * 100 + it * 4 + w;
        float s1sv = sv[b * 200 + i];
        float s1pv = sv[51200 + b * 200 + i];
        float ds = 0.f, dp = 0.f, pa0 = 0.f, pa1 = 0.f, pb0 = 0.f, pb1 = 0.f;
#pragma unroll
        for (int q = 0; q < 4; ++q) {
            int j = lane + 64 * q;
            if (j < 200) {
                unsigned int mw = maskw[(size_t)(b * 200 + i) * 8 + (j >> 5)];
                if ((mw >> (j & 31)) & 1u) {
                    float x1 = s1sv + s2s[j]; x1 = fmaxf(x1, 0.3f * x1);
                    float x2 = s1pv + s2p[j]; x2 = fmaxf(x2, 0.3f * x2);
                    float p1 = __expf(x1 - EXP_SHIFT), p2 = __expf(x2 - EXP_SHIFT);
                    ds += p1; dp += p2;
                    float4 hv = *(float4*)&hsp[j * 4];
                    pa0 += p1 * hv.x; pa1 += p1 * hv.y;
                    pb0 += p2 * hv.z; pb1 += p2 * hv.w;
                }
            }
        }
        for (int off = 32; off; off >>= 1) {
            ds  += __shfl_xor(ds, off, 64);  dp  += __shfl_xor(dp, off, 64);
            pa0 += __shfl_xor(pa0, off, 64); pa1 += __shfl_xor(pa1, off, 64);
            pb0 += __shfl_xor(pb0, off, 64); pb1 += __shfl_xor(pb1, off, 64);
        }
        if (lane == 0) {
            float gs = BN_SCALEF * bns_g[i], bs = bns_b[i];
            float v0 = (pa0 / ds) * gs + bs, v1 = (pa1 / ds) * gs + bs;
            out[(size_t)(b * 200 + i) * 2 + 0] = 1.f / (1.f + __expf(-v0));
            out[(size_t)(b * 200 + i) * 2 + 1] = 1.f / (1.f + __expf(-v1));
            float gp = BN_SCALEF * bnp_g[i], bp = bnp_b[i];
            float u0 = (pb0 / dp) * gp + bp, u1 = (pb1 / dp) * gp + bp;
            out[51200 + (size_t)(b * 200 + i) * 2 + 0] = u0 > 0.f ? u0 : __expf(u0) - 1.f;
            out[51200 + (size_t)(b * 200 + i) * 2 + 1] = u1 > 0.f ? u1 : __expf(u1) - 1.f;
        }
    }
}

// ---------------------------------------------------------------- launch

extern "C" void kernel_launch(void* const* d_in, const int* in_sizes, int n_in,
                              void* d_out, int out_size, void* d_ws, size_t ws_size,
                              hipStream_t stream) {
    (void)in_sizes; (void)n_in; (void)out_size; (void)ws_size;
    const float* feat    = (const float*)d_in[0];
    const int*   adj     = (const int*)d_in[1];
    const float* W_heads = (const float*)d_in[2];
    const float* a_heads = (const float*)d_in[3];
    const float* bnh_g   = (const float*)d_in[4];
    const float* bnh_b   = (const float*)d_in[5];
    const float* bnt_g   = (const float*)d_in[6];
    const float* bnt_b   = (const float*)d_in[7];
    const float* W_sent  = (const float*)d_in[8];
    const float* a_sent  = (const float*)d_in[9];
    const float* bns_g   = (const float*)d_in[10];
    const float* bns_b   = (const float*)d_in[11];
    const float* W_para  = (const float*)d_in[12];
    const float* a_para  = (const float*)d_in[13];
    const float* bnp_g   = (const float*)d_in[14];
    const float* bnp_b   = (const float*)d_in[15];
    const float* W_q     = (const float*)d_in[16];
    const float* a_q     = (const float*)d_in[17];
    const float* bnq_g   = (const float*)d_in[18];
    const float* bnq_b   = (const float*)d_in[19];
    const float* W2      = (const float*)d_in[20];
    float* out = (float*)d_out;
    float* ws  = (float*)d_ws;

    _Float16* h16 = (_Float16*)ws;              // 6,553,600 h = 3,276,800 f
    _Float16* x16 = (_Float16*)(ws + 3276800);  // 6,553,600 h
    float* w2t   = ws + 6553600;                // 9,216 f
    _Float16* Bt = (_Float16*)(ws + 6562816);   // 196,608 h = 98,304 f
    unsigned int* maskw = (unsigned int*)(ws + 6661120);  // 204,800 words
    float* h2    = ws + 6865920;                // 921,600 f
    float* sv    = ws + 7787520;                // 153,600 f (end ~31.8 MB)

    prep<<<dim3(1793), dim3(256), 0, stream>>>(adj, W_heads, W_sent, W_para, W_q,
                                               maskw, Bt, w2t);
    gemm1_stream<<<dim3(800), dim3(256), 0, stream>>>(feat, Bt, h16);
    attn_heads_mfma<<<dim3(1024), dim3(256), 0, stream>>>(h16, a_heads, maskw,
                                                          bnh_g, bnh_b, bnt_g, bnt_b, x16);
    gemm2s<<<dim3(200), dim3(256), 0, stream>>>(x16, w2t, a_sent, a_para, a_q, h2, sv);
    attn_spq<<<dim3(128, 3), dim3(256), 0, stream>>>(h2, sv, maskw, bns_g, bns_b,
                                                     bnp_g, bnp_b, bnq_g, bnq_b, W2, out);
}